// Round 4
// baseline (930.115 us; speedup 1.0000x reference)
//
#include <hip/hip_runtime.h>
#include <math.h>

#define NN 100000
#define NE 1600000
#define D 64
#define INDIM 18
#define CHUNKS 256          // edge chunks (= grid of count/bin kernels)
#define NBKT 391            // ceil(NN / 256) buckets
#define BNODES 256          // nodes per bucket

__device__ __forceinline__ float gelu_exact(float x) {
    return 0.5f * x * (1.0f + erff(x * 0.70710678118654752f));
}

// ---------------- project: h[n,:] = mlp(concat(x,grid)) ----------------
__global__ __launch_bounds__(256) void project_kernel(
    const float* __restrict__ x, const float* __restrict__ grid,
    const float* __restrict__ w1, const float* __restrict__ b1,
    const float* __restrict__ w2, const float* __restrict__ b2,
    float* __restrict__ h)
{
    int n = blockIdx.x * 256 + threadIdx.x;
    if (n >= NN) return;

    float in[INDIM];
    {
        const float4* xr = (const float4*)(x + (size_t)n * 16);
        float4 a = xr[0], b = xr[1], c = xr[2], d = xr[3];
        in[0]=a.x; in[1]=a.y; in[2]=a.z; in[3]=a.w;
        in[4]=b.x; in[5]=b.y; in[6]=b.z; in[7]=b.w;
        in[8]=c.x; in[9]=c.y; in[10]=c.z; in[11]=c.w;
        in[12]=d.x; in[13]=d.y; in[14]=d.z; in[15]=d.w;
        float2 g = *(const float2*)(grid + (size_t)n * 2);
        in[16]=g.x; in[17]=g.y;
    }

    float acc[D];
    #pragma unroll
    for (int j = 0; j < D; ++j) acc[j] = b2[j];

    for (int j1 = 0; j1 < D; ++j1) {     // j1 runtime: only uniform weight idx
        float a = b1[j1];
        #pragma unroll
        for (int k = 0; k < INDIM; ++k) a += in[k] * w1[k * D + j1];
        float t = gelu_exact(a);
        #pragma unroll
        for (int j = 0; j < D; ++j) acc[j] += t * w2[j1 * D + j];
    }

    float* hrow = h + (size_t)n * D;
    #pragma unroll
    for (int j = 0; j < D; j += 4) {
        float4 v = { acc[j], acc[j+1], acc[j+2], acc[j+3] };
        *(float4*)(hrow + j) = v;
    }
}

// ---- sort step 1: per-chunk LDS histogram -> counts[chunk][bucket] ----
// counts rows are single-writer, coalesced stores (no multi-writer lines).
__global__ __launch_bounds__(256) void count_kernel(
    const int* __restrict__ ei, int* __restrict__ counts)
{
    __shared__ int s_hist[NBKT];
    const int blk = blockIdx.x, tid = threadIdx.x;
    const int* __restrict__ dst = ei + NE;
    for (int i = tid; i < NBKT; i += 256) s_hist[i] = 0;
    __syncthreads();
    for (int e = blk * 256 + tid; e < NE; e += CHUNKS * 256)
        atomicAdd(&s_hist[dst[e] >> 8], 1);
    __syncthreads();
    for (int b = tid; b < NBKT; b += 256)
        counts[blk * NBKT + b] = s_hist[b];
}

// ---- sort step 2: per-bucket column scan over chunks (in place) ------
// block g: counts[c][g] -> exclusive prefix; btotal[g] = column total.
__global__ __launch_bounds__(256) void scan_cols_kernel(
    int* __restrict__ counts, int* __restrict__ btotal)
{
    __shared__ int s[256];
    const int g = blockIdx.x, tid = threadIdx.x;
    int v = counts[tid * NBKT + g];
    s[tid] = v; __syncthreads();
    for (int off = 1; off < 256; off <<= 1) {
        int val = s[tid];
        int add = (tid >= off) ? s[tid - off] : 0;
        __syncthreads();
        s[tid] = val + add;
        __syncthreads();
    }
    counts[tid * NBKT + g] = s[tid] - v;     // exclusive
    if (tid == 255) btotal[g] = s[255];
}

// ---- sort step 3: scan bucket totals -> offs[0..NBKT] ----------------
__global__ __launch_bounds__(256) void scan_bsum_kernel(
    const int* __restrict__ btotal, int* __restrict__ offs)
{
    __shared__ int s[256];
    const int tid = threadIdx.x;
    int b0 = 2 * tid, b1 = 2 * tid + 1;
    int v0 = (b0 < NBKT) ? btotal[b0] : 0;
    int v1 = (b1 < NBKT) ? btotal[b1] : 0;
    int sum = v0 + v1;
    s[tid] = sum; __syncthreads();
    for (int off = 1; off < 256; off <<= 1) {
        int val = s[tid];
        int add = (tid >= off) ? s[tid - off] : 0;
        __syncthreads();
        s[tid] = val + add;
        __syncthreads();
    }
    int base = s[tid] - sum;
    if (b0 < NBKT) offs[b0] = base;
    if (b1 < NBKT) offs[b1] = base + v0;
    if (tid == 0)  offs[NBKT] = NE;
}

// ---- sort step 4: scatter packed (src<<8 | dst&255), LDS cursors -----
// Each (chunk,bucket) output region has exactly one writer block.
__global__ __launch_bounds__(256) void bin_kernel(
    const int* __restrict__ ei, const int* __restrict__ counts,
    const int* __restrict__ offs, int* __restrict__ packed)
{
    __shared__ int s_cur[NBKT];
    const int blk = blockIdx.x, tid = threadIdx.x;
    const int* __restrict__ dst = ei + NE;
    for (int b = tid; b < NBKT; b += 256)
        s_cur[b] = offs[b] + counts[blk * NBKT + b];
    __syncthreads();
    for (int e = blk * 256 + tid; e < NE; e += CHUNKS * 256) {
        int d = dst[e];
        int s = ei[e];
        int pos = atomicAdd(&s_cur[d >> 8], 1);   // LDS atomic
        packed[pos] = (s << 8) | (d & 255);
    }
}

// ---- aggregate: block b owns nodes [256b, 256b+256), LDS slice -------
__global__ __launch_bounds__(512) void agg_bucket_kernel(
    const int* __restrict__ offs, const int* __restrict__ packed,
    const float* __restrict__ h, float* __restrict__ aggr)
{
    __shared__ float slice[BNODES * D];     // 64 KB
    const int b = blockIdx.x, tid = threadIdx.x;
    for (int i = tid; i < BNODES * D; i += 512) slice[i] = 0.f;
    __syncthreads();

    const int start = offs[b], end = offs[b + 1];
    const int wid = tid >> 6, lane = tid & 63;
    // 4 edges per wave-iteration for gather ILP; per-element guards at tail
    for (int e0 = start + wid * 4; e0 < end; e0 += 8 * 4) {
        int pa0 = (e0     < end) ? packed[e0]     : -1;
        int pa1 = (e0 + 1 < end) ? packed[e0 + 1] : -1;
        int pa2 = (e0 + 2 < end) ? packed[e0 + 2] : -1;
        int pa3 = (e0 + 3 < end) ? packed[e0 + 3] : -1;
        float v0 = (pa0 >= 0) ? h[(size_t)(pa0 >> 8) * D + lane] : 0.f;
        float v1 = (pa1 >= 0) ? h[(size_t)(pa1 >> 8) * D + lane] : 0.f;
        float v2 = (pa2 >= 0) ? h[(size_t)(pa2 >> 8) * D + lane] : 0.f;
        float v3 = (pa3 >= 0) ? h[(size_t)(pa3 >> 8) * D + lane] : 0.f;
        if (pa0 >= 0) atomicAdd(&slice[(pa0 & 255) * D + lane], v0);
        if (pa1 >= 0) atomicAdd(&slice[(pa1 & 255) * D + lane], v1);
        if (pa2 >= 0) atomicAdd(&slice[(pa2 & 255) * D + lane], v2);
        if (pa3 >= 0) atomicAdd(&slice[(pa3 & 255) * D + lane], v3);
    }
    __syncthreads();

    const int base = b * BNODES;
    for (int i = tid; i < BNODES * D; i += 512) {
        int node = base + (i >> 6);
        if (node < NN) aggr[(size_t)node * D + (i & 63)] = slice[i];
    }
}

// ---------------- legacy atomic aggregate (ws fallback) ----------------
__global__ __launch_bounds__(256) void aggregate_kernel(
    const int* __restrict__ ei, const float* __restrict__ h,
    float* __restrict__ aggr)
{
    int t = blockIdx.x * 256 + threadIdx.x;
    int e = t >> 6;
    int lane = t & 63;
    if (e >= NE) return;
    int src = ei[e];
    int dst = ei[NE + e];
    float v = h[(size_t)src * D + lane];
    atomicAdd(&aggr[(size_t)dst * D + lane], v);
}

// ---------------- update (W-mlp + aggr, gelu) + decode, fused ----------
__global__ __launch_bounds__(256) void update_decode_kernel(
    const float* __restrict__ h, const float* __restrict__ aggr,
    const float* __restrict__ ww1, const float* __restrict__ wb1,
    const float* __restrict__ ww2, const float* __restrict__ wb2,
    const float* __restrict__ dw1, const float* __restrict__ db1,
    const float* __restrict__ dw2, const float* __restrict__ db2,
    float* __restrict__ out)
{
    int n = blockIdx.x * 256 + threadIdx.x;
    if (n >= NN) return;

    float hrow[D];
    #pragma unroll
    for (int j = 0; j < D; j += 4) {
        float4 v = *(const float4*)(h + (size_t)n * D + j);
        hrow[j] = v.x; hrow[j+1] = v.y; hrow[j+2] = v.z; hrow[j+3] = v.w;
    }

    float acc[D];
    #pragma unroll
    for (int j = 0; j < D; j += 4) {
        float4 v = *(const float4*)(aggr + (size_t)n * D + j);
        acc[j]   = wb2[j]   + v.x;
        acc[j+1] = wb2[j+1] + v.y;
        acc[j+2] = wb2[j+2] + v.z;
        acc[j+3] = wb2[j+3] + v.w;
    }

    for (int j1 = 0; j1 < D; ++j1) {
        float a = wb1[j1];
        #pragma unroll
        for (int k = 0; k < D; ++k) a += hrow[k] * ww1[k * D + j1];
        float t = gelu_exact(a);
        #pragma unroll
        for (int j = 0; j < D; ++j) acc[j] += t * ww2[j1 * D + j];
    }

    #pragma unroll
    for (int j = 0; j < D; ++j) acc[j] = gelu_exact(acc[j]);

    float o = db2[0];
    for (int j1 = 0; j1 < D; ++j1) {
        float a = db1[j1];
        #pragma unroll
        for (int k = 0; k < D; ++k) a += acc[k] * dw1[k * D + j1];
        o += gelu_exact(a) * dw2[j1];
    }
    out[n] = o;
}

extern "C" void kernel_launch(void* const* d_in, const int* in_sizes, int n_in,
                              void* d_out, int out_size, void* d_ws, size_t ws_size,
                              hipStream_t stream) {
    const float* x    = (const float*)d_in[0];
    const float* grid = (const float*)d_in[1];
    const int*   ei   = (const int*)d_in[2];
    const float* p_w1 = (const float*)d_in[4];
    const float* p_b1 = (const float*)d_in[5];
    const float* p_w2 = (const float*)d_in[6];
    const float* p_b2 = (const float*)d_in[7];
    const float* w_w1 = (const float*)d_in[8];
    const float* w_b1 = (const float*)d_in[9];
    const float* w_w2 = (const float*)d_in[10];
    const float* w_b2 = (const float*)d_in[11];
    const float* d_w1 = (const float*)d_in[12];
    const float* d_b1 = (const float*)d_in[13];
    const float* d_w2 = (const float*)d_in[14];
    const float* d_b2 = (const float*)d_in[15];
    float* out = (float*)d_out;

    float* h    = (float*)d_ws;                       // [NN, D]
    float* aggr = h + (size_t)NN * D;                 // [NN, D]
    int* counts = (int*)(aggr + (size_t)NN * D);      // [CHUNKS][NBKT]
    int* btotal = counts + (size_t)CHUNKS * NBKT;     // [NBKT]
    int* offs   = btotal + NBKT;                      // [NBKT+1]
    int* packed = offs + NBKT + 1;                    // [NE]

    size_t need = ((size_t)NN * D * 2 + (size_t)CHUNKS * NBKT
                   + NBKT + (NBKT + 1) + NE) * 4;

    project_kernel<<<(NN + 255) / 256, 256, 0, stream>>>(
        x, grid, p_w1, p_b1, p_w2, p_b2, h);

    if (ws_size >= need) {
        count_kernel   <<<CHUNKS, 256, 0, stream>>>(ei, counts);
        scan_cols_kernel<<<NBKT,  256, 0, stream>>>(counts, btotal);
        scan_bsum_kernel<<<1,     256, 0, stream>>>(btotal, offs);
        bin_kernel     <<<CHUNKS, 256, 0, stream>>>(ei, counts, offs, packed);
        agg_bucket_kernel<<<NBKT, 512, 0, stream>>>(offs, packed, h, aggr);
    } else {
        hipMemsetAsync(aggr, 0, (size_t)NN * D * sizeof(float), stream);
        aggregate_kernel<<<(size_t)NE * 64 / 256, 256, 0, stream>>>(ei, h, aggr);
    }

    update_decode_kernel<<<(NN + 255) / 256, 256, 0, stream>>>(
        h, aggr, w_w1, w_b1, w_w2, w_b2, d_w1, d_b1, d_w2, d_b2, out);
}

// Round 5
// 315.039 us; speedup vs baseline: 2.9524x; 2.9524x over previous
//
#include <hip/hip_runtime.h>
#include <math.h>

#define NN 100000
#define NE 1600000
#define D 64
#define INDIM 18
#define CHUNKS 256            // edge chunks for count/bin
#define BN 64                 // nodes per bucket
#define NBKT 1563             // ceil(NN / BN)
#define CAP 1536              // LDS edge capacity per bucket (mean ~1024, +16 sigma)

__device__ __forceinline__ float gelu_exact(float x) {
    return 0.5f * x * (1.0f + erff(x * 0.70710678118654752f));
}

// ---------------- project: h[n,:] = mlp(concat(x,grid)) ----------------
__global__ __launch_bounds__(256) void project_kernel(
    const float* __restrict__ x, const float* __restrict__ grid,
    const float* __restrict__ w1, const float* __restrict__ b1,
    const float* __restrict__ w2, const float* __restrict__ b2,
    float* __restrict__ h)
{
    int n = blockIdx.x * 256 + threadIdx.x;
    if (n >= NN) return;

    float in[INDIM];
    {
        const float4* xr = (const float4*)(x + (size_t)n * 16);
        float4 a = xr[0], b = xr[1], c = xr[2], d = xr[3];
        in[0]=a.x; in[1]=a.y; in[2]=a.z; in[3]=a.w;
        in[4]=b.x; in[5]=b.y; in[6]=b.z; in[7]=b.w;
        in[8]=c.x; in[9]=c.y; in[10]=c.z; in[11]=c.w;
        in[12]=d.x; in[13]=d.y; in[14]=d.z; in[15]=d.w;
        float2 g = *(const float2*)(grid + (size_t)n * 2);
        in[16]=g.x; in[17]=g.y;
    }

    float acc[D];
    #pragma unroll
    for (int j = 0; j < D; ++j) acc[j] = b2[j];

    for (int j1 = 0; j1 < D; ++j1) {
        float a = b1[j1];
        #pragma unroll
        for (int k = 0; k < INDIM; ++k) a += in[k] * w1[k * D + j1];
        float t = gelu_exact(a);
        #pragma unroll
        for (int j = 0; j < D; ++j) acc[j] += t * w2[j1 * D + j];
    }

    float* hrow = h + (size_t)n * D;
    #pragma unroll
    for (int j = 0; j < D; j += 4) {
        float4 v = { acc[j], acc[j+1], acc[j+2], acc[j+3] };
        *(float4*)(hrow + j) = v;
    }
}

// ---- sort step 1: per-chunk LDS histogram -> counts[chunk][bucket] ----
__global__ __launch_bounds__(256) void count_kernel(
    const int* __restrict__ ei, unsigned short* __restrict__ counts)
{
    __shared__ int s_hist[NBKT];
    const int blk = blockIdx.x, tid = threadIdx.x;
    const int* __restrict__ dst = ei + NE;
    for (int i = tid; i < NBKT; i += 256) s_hist[i] = 0;
    __syncthreads();
    for (int e = blk * 256 + tid; e < NE; e += CHUNKS * 256)
        atomicAdd(&s_hist[dst[e] / BN], 1);
    __syncthreads();
    for (int b = tid; b < NBKT; b += 256)
        counts[blk * NBKT + b] = (unsigned short)s_hist[b];
}

// ---- sort step 2: per-bucket column scan over chunks (in place) ------
__global__ __launch_bounds__(256) void scan_cols_kernel(
    unsigned short* __restrict__ counts, int* __restrict__ btotal)
{
    __shared__ int s[256];
    const int g = blockIdx.x, tid = threadIdx.x;
    int v = counts[tid * NBKT + g];
    s[tid] = v; __syncthreads();
    for (int off = 1; off < 256; off <<= 1) {
        int val = s[tid];
        int add = (tid >= off) ? s[tid - off] : 0;
        __syncthreads();
        s[tid] = val + add;
        __syncthreads();
    }
    counts[tid * NBKT + g] = (unsigned short)(s[tid] - v);   // exclusive
    if (tid == 255) btotal[g] = s[255];
}

// ---- sort step 3: scan bucket totals -> offs[0..NBKT] ----------------
__global__ __launch_bounds__(1024) void scan_bsum_kernel(
    const int* __restrict__ btotal, int* __restrict__ offs)
{
    __shared__ int s[1024];
    const int tid = threadIdx.x;
    int b0 = 2 * tid, b1 = 2 * tid + 1;
    int v0 = (b0 < NBKT) ? btotal[b0] : 0;
    int v1 = (b1 < NBKT) ? btotal[b1] : 0;
    int sum = v0 + v1;
    s[tid] = sum; __syncthreads();
    for (int off = 1; off < 1024; off <<= 1) {
        int val = s[tid];
        int add = (tid >= off) ? s[tid - off] : 0;
        __syncthreads();
        s[tid] = val + add;
        __syncthreads();
    }
    int base = s[tid] - sum;
    if (b0 < NBKT) offs[b0] = base;
    if (b1 < NBKT) offs[b1] = base + v0;
    if (tid == 0)  offs[NBKT] = NE;
}

// ---- sort step 4: scatter packed (src<<6 | dst%64), LDS cursors ------
__global__ __launch_bounds__(256) void bin_kernel(
    const int* __restrict__ ei, const unsigned short* __restrict__ counts,
    const int* __restrict__ offs, int* __restrict__ packed)
{
    __shared__ int s_cur[NBKT];
    const int blk = blockIdx.x, tid = threadIdx.x;
    const int* __restrict__ dst = ei + NE;
    for (int b = tid; b < NBKT; b += 256)
        s_cur[b] = offs[b] + (int)counts[blk * NBKT + b];
    __syncthreads();
    for (int e = blk * 256 + tid; e < NE; e += CHUNKS * 256) {
        int d = dst[e];
        int s = ei[e];
        int pos = atomicAdd(&s_cur[d / BN], 1);
        packed[pos] = (s << 6) | (d & (BN - 1));
    }
}

// ---- fused per-bucket node-sort (LDS) + wave-per-node aggregation ----
__global__ __launch_bounds__(256) void sortagg_kernel(
    const int* __restrict__ offs, const int* __restrict__ packed,
    const float* __restrict__ h, float* __restrict__ aggr)
{
    __shared__ int s_off[BN + 1];
    __shared__ int s_cur[BN];
    __shared__ int s_src[CAP];
    const int b = blockIdx.x, tid = threadIdx.x;
    const int start = offs[b], end = offs[b + 1];
    const int cnt = end - start;
    const int wid = tid >> 6, lane = tid & 63;
    const int base = b * BN;

    if (cnt <= CAP) {
        if (tid < BN) s_cur[tid] = 0;
        __syncthreads();
        for (int e = start + tid; e < end; e += 256)
            atomicAdd(&s_cur[packed[e] & (BN - 1)], 1);
        __syncthreads();
        // wave 0: exclusive scan of 64 counts via shfl
        if (tid < 64) {
            int v = s_cur[tid];
            int incl = v;
            #pragma unroll
            for (int off = 1; off < 64; off <<= 1) {
                int u = __shfl_up(incl, off, 64);
                if (tid >= off) incl += u;
            }
            s_off[tid] = incl - v;
            if (tid == 63) s_off[64] = cnt;
        }
        __syncthreads();
        if (tid < BN) s_cur[tid] = s_off[tid];
        __syncthreads();
        for (int e = start + tid; e < end; e += 256) {
            int p = packed[e];
            int pos = atomicAdd(&s_cur[p & (BN - 1)], 1);
            s_src[pos] = p >> 6;
        }
        __syncthreads();
        // wave-per-node aggregation, 8-deep gather ILP
        for (int m = wid; m < BN; m += 4) {
            int node = base + m;
            if (node < NN) {
                int s0 = s_off[m], s1 = s_off[m + 1];
                float a0=0,a1=0,a2=0,a3=0,a4=0,a5=0,a6=0,a7=0;
                int e = s0;
                for (; e + 8 <= s1; e += 8) {
                    int i0=s_src[e],  i1=s_src[e+1],i2=s_src[e+2],i3=s_src[e+3];
                    int i4=s_src[e+4],i5=s_src[e+5],i6=s_src[e+6],i7=s_src[e+7];
                    a0 += h[(size_t)i0*D+lane]; a1 += h[(size_t)i1*D+lane];
                    a2 += h[(size_t)i2*D+lane]; a3 += h[(size_t)i3*D+lane];
                    a4 += h[(size_t)i4*D+lane]; a5 += h[(size_t)i5*D+lane];
                    a6 += h[(size_t)i6*D+lane]; a7 += h[(size_t)i7*D+lane];
                }
                for (; e < s1; ++e) a0 += h[(size_t)s_src[e]*D+lane];
                aggr[(size_t)node*D+lane] = ((a0+a1)+(a2+a3))+((a4+a5)+(a6+a7));
            }
        }
    } else {
        // correct slow fallback (LDS overflow; not expected for this input)
        for (int m = wid; m < BN; m += 4) {
            int node = base + m;
            if (node < NN) {
                float a = 0.f;
                for (int e = start; e < end; ++e) {
                    int p = packed[e];
                    if ((p & (BN - 1)) == m) a += h[(size_t)(p >> 6) * D + lane];
                }
                aggr[(size_t)node * D + lane] = a;
            }
        }
    }
}

// ---------------- legacy atomic aggregate (ws fallback) ----------------
__global__ __launch_bounds__(256) void aggregate_kernel(
    const int* __restrict__ ei, const float* __restrict__ h,
    float* __restrict__ aggr)
{
    int t = blockIdx.x * 256 + threadIdx.x;
    int e = t >> 6;
    int lane = t & 63;
    if (e >= NE) return;
    int src = ei[e];
    int dst = ei[NE + e];
    float v = h[(size_t)src * D + lane];
    atomicAdd(&aggr[(size_t)dst * D + lane], v);
}

// ---------------- update (W-mlp + aggr, gelu) + decode, fused ----------
__global__ __launch_bounds__(256) void update_decode_kernel(
    const float* __restrict__ h, const float* __restrict__ aggr,
    const float* __restrict__ ww1, const float* __restrict__ wb1,
    const float* __restrict__ ww2, const float* __restrict__ wb2,
    const float* __restrict__ dw1, const float* __restrict__ db1,
    const float* __restrict__ dw2, const float* __restrict__ db2,
    float* __restrict__ out)
{
    int n = blockIdx.x * 256 + threadIdx.x;
    if (n >= NN) return;

    float hrow[D];
    #pragma unroll
    for (int j = 0; j < D; j += 4) {
        float4 v = *(const float4*)(h + (size_t)n * D + j);
        hrow[j] = v.x; hrow[j+1] = v.y; hrow[j+2] = v.z; hrow[j+3] = v.w;
    }

    float acc[D];
    #pragma unroll
    for (int j = 0; j < D; j += 4) {
        float4 v = *(const float4*)(aggr + (size_t)n * D + j);
        acc[j]   = wb2[j]   + v.x;
        acc[j+1] = wb2[j+1] + v.y;
        acc[j+2] = wb2[j+2] + v.z;
        acc[j+3] = wb2[j+3] + v.w;
    }

    for (int j1 = 0; j1 < D; ++j1) {
        float a = wb1[j1];
        #pragma unroll
        for (int k = 0; k < D; ++k) a += hrow[k] * ww1[k * D + j1];
        float t = gelu_exact(a);
        #pragma unroll
        for (int j = 0; j < D; ++j) acc[j] += t * ww2[j1 * D + j];
    }

    #pragma unroll
    for (int j = 0; j < D; ++j) acc[j] = gelu_exact(acc[j]);

    float o = db2[0];
    for (int j1 = 0; j1 < D; ++j1) {
        float a = db1[j1];
        #pragma unroll
        for (int k = 0; k < D; ++k) a += acc[k] * dw1[k * D + j1];
        o += gelu_exact(a) * dw2[j1];
    }
    out[n] = o;
}

extern "C" void kernel_launch(void* const* d_in, const int* in_sizes, int n_in,
                              void* d_out, int out_size, void* d_ws, size_t ws_size,
                              hipStream_t stream) {
    const float* x    = (const float*)d_in[0];
    const float* grid = (const float*)d_in[1];
    const int*   ei   = (const int*)d_in[2];
    const float* p_w1 = (const float*)d_in[4];
    const float* p_b1 = (const float*)d_in[5];
    const float* p_w2 = (const float*)d_in[6];
    const float* p_b2 = (const float*)d_in[7];
    const float* w_w1 = (const float*)d_in[8];
    const float* w_b1 = (const float*)d_in[9];
    const float* w_w2 = (const float*)d_in[10];
    const float* w_b2 = (const float*)d_in[11];
    const float* d_w1 = (const float*)d_in[12];
    const float* d_b1 = (const float*)d_in[13];
    const float* d_w2 = (const float*)d_in[14];
    const float* d_b2 = (const float*)d_in[15];
    float* out = (float*)d_out;

    float* h    = (float*)d_ws;                            // [NN, D] f32
    float* aggr = h + (size_t)NN * D;                      // [NN, D] f32
    unsigned short* counts = (unsigned short*)(aggr + (size_t)NN * D); // [CHUNKS][NBKT] u16
    int* btotal = (int*)(counts + (size_t)CHUNKS * NBKT);  // [NBKT]
    int* offs   = btotal + NBKT;                           // [NBKT+1]
    int* packed = offs + NBKT + 1;                         // [NE]

    size_t need = (size_t)NN * D * 2 * 4 + (size_t)CHUNKS * NBKT * 2
                + ((size_t)NBKT + (NBKT + 1) + NE) * 4;

    project_kernel<<<(NN + 255) / 256, 256, 0, stream>>>(
        x, grid, p_w1, p_b1, p_w2, p_b2, h);

    if (ws_size >= need) {
        count_kernel    <<<CHUNKS, 256, 0, stream>>>(ei, counts);
        scan_cols_kernel<<<NBKT,   256, 0, stream>>>(counts, btotal);
        scan_bsum_kernel<<<1,     1024, 0, stream>>>(btotal, offs);
        bin_kernel      <<<CHUNKS, 256, 0, stream>>>(ei, counts, offs, packed);
        sortagg_kernel  <<<NBKT,   256, 0, stream>>>(offs, packed, h, aggr);
    } else {
        hipMemsetAsync(aggr, 0, (size_t)NN * D * sizeof(float), stream);
        aggregate_kernel<<<(size_t)NE * 64 / 256, 256, 0, stream>>>(ei, h, aggr);
    }

    update_decode_kernel<<<(NN + 255) / 256, 256, 0, stream>>>(
        h, aggr, w_w1, w_b1, w_w2, w_b2, d_w1, d_b1, d_w2, d_b2, out);
}